// Round 4
// baseline (717.441 us; speedup 1.0000x reference)
//
#include <hip/hip_runtime.h>
#include <math.h>

// Problem constants (from reference setup_inputs): n=16, b=4, t=2048, h=1024
#define H     1024
#define NBLK  16
#define BT    8192                 // b * t
#define ROUTED_SIZE (BT * H)       // 8,388,608 floats
#define SCALE_INV (1.0f / 32.0f)   // 1 / (sqrt(1024) * BASE_TAU)
#define TCOLS 4                    // (b,t) columns pipelined per block

typedef float v4f __attribute__((ext_vector_type(4)));

// Raw barrier: drain own LDS ops, then s_barrier. Deliberately does NOT
// drain vmcnt -> later columns' global loads stay in flight (T3/T4 idiom;
// __syncthreads would emit s_waitcnt vmcnt(0) and kill the pipeline).
#define BAR() asm volatile("s_waitcnt lgkmcnt(0)\n\ts_barrier" ::: "memory")

// ---------------------------------------------------------------------------
// Pre-kernel: qb[n] = sum_h w_query[pos][h] * key_pos_bias[n][h]  (n = 0..15)
// ---------------------------------------------------------------------------
__global__ __launch_bounds__(1024) void qb_kernel(
    const float* __restrict__ w_query,
    const float* __restrict__ key_pos_bias,
    const int*   __restrict__ pos_p,
    float*       __restrict__ qb)
{
    const int n    = threadIdx.x >> 6;   // wave id = history slot
    const int lane = threadIdx.x & 63;
    const int pos  = *pos_p;

    const float* q = w_query      + (size_t)pos * H;
    const float* b = key_pos_bias + (size_t)n   * H;

    float s = 0.0f;
#pragma unroll
    for (int j = 0; j < 4; ++j) {
        const int h = lane * 16 + j * 4;
        const float4 qv = *(const float4*)(q + h);
        const float4 bv = *(const float4*)(b + h);
        s += qv.x * bv.x + qv.y * bv.y + qv.z * bv.z + qv.w * bv.w;
    }
#pragma unroll
    for (int off = 32; off; off >>= 1) s += __shfl_xor(s, off, 64);
    if (lane == 0) qb[n] = s;
}

// ---------------------------------------------------------------------------
// Main kernel v5: 1024-thread block pipelines TCOLS=4 (b,t) columns.
//   thread (g = tid>>8, c = tid&255): planes 4g..4g+3, h = 4c..4c+3, per col.
//   - ALL 16 global_load_dwordx4 issued in the prologue (256 KiB/block MLP)
//   - per-column machinery uses raw s_barrier + lgkmcnt(0) so the later
//     columns' loads remain outstanding across barriers (counted vmcnt at
//     first use of each column's registers, compiler-emitted)
//   - single-wave softmax (lanes 0..15 of wave 0), broadcast via LDS
// values is read from HBM exactly once.
// ---------------------------------------------------------------------------
__global__ __launch_bounds__(1024) void block_attn_res_kernel(
    const float* __restrict__ values,   // [16, 4, 2048, 1024]
    const float* __restrict__ w_query,  // [24, 1024]
    const int*   __restrict__ pos_p,    // scalar (16)
    const float* __restrict__ qb,       // [16] precomputed q·bias
    float*       __restrict__ out)      // routed [4,2048,1024] ++ alpha [4,2048,16]
{
    const int tid = threadIdx.x;       // 0..1023
    const int c   = tid & 255;         // h-column group
    const int g   = tid >> 8;          // 0..3 plane group (wave-uniform)
    const int h0  = c << 2;
    const int bt0 = blockIdx.x * TCOLS;

    __shared__ float2 pv[NBLK][256];   // 32 KiB (ss,qv) partials, reused per col
    __shared__ v4f    rp[4][256];      // 16 KiB routed partials, reused per col
    __shared__ float  scores[NBLK];
    __shared__ float  alf[NBLK];       // alpha (e*rs), reused per col

    // ---- prologue: issue ALL value loads first (nothing depends on pos) ----
    v4f v[TCOLS][4];                   // 64 VGPRs payload, static indexing only
    const float* base = values + (size_t)(g * 4) * BT * H + (size_t)bt0 * H + h0;
#pragma unroll
    for (int j = 0; j < TCOLS; ++j)    // j-major: col j completes first
#pragma unroll
        for (int i = 0; i < 4; ++i)
            v[j][i] = *(const v4f*)(base + (size_t)i * BT * H + (size_t)j * H);

    const int pos = *pos_p;
    const v4f q = *(const v4f*)(w_query + (size_t)pos * H + h0);

#pragma unroll
    for (int j = 0; j < TCOLS; ++j) {
        const size_t bt = (size_t)bt0 + j;

        // ---- (ss, qv) partials for this column (waits only col j's loads) ----
#pragma unroll
        for (int i = 0; i < 4; ++i) {
            const v4f x  = v[j][i];
            const v4f xx = x * x;
            const v4f qx = q * x;
            pv[g * 4 + i][c] = make_float2((xx[0] + xx[1]) + (xx[2] + xx[3]),
                                           (qx[0] + qx[1]) + (qx[2] + qx[3]));
        }
        BAR();

        // ---- wave w reduces plane w: 4 ds_read_b64 + 6-level shuffle ----
        {
            const int w    = tid >> 6;
            const int lane = tid & 63;
            const float2 p0 = pv[w][lane];
            const float2 p1 = pv[w][lane + 64];
            const float2 p2 = pv[w][lane + 128];
            const float2 p3 = pv[w][lane + 192];
            float ss = (p0.x + p1.x) + (p2.x + p3.x);
            float qv = (p0.y + p1.y) + (p2.y + p3.y);
#pragma unroll
            for (int off = 32; off; off >>= 1) {
                ss += __shfl_xor(ss, off, 64);
                qv += __shfl_xor(qv, off, 64);
            }
            if (lane == 0) {
                const float inv = rsqrtf(ss * (1.0f / (float)H) + 1e-6f);
                scores[w] = (inv * qv + qb[w]) * SCALE_INV;
            }
        }
        BAR();

        // ---- single-wave softmax: lanes 0..15 of wave 0 ----
        if (tid < NBLK) {
            const float s = scores[tid];
            float mx = s;
#pragma unroll
            for (int off = 1; off <= 8; off <<= 1)
                mx = fmaxf(mx, __shfl_xor(mx, off, 64));
            const float e = __expf(s - mx);
            float sm = e;
#pragma unroll
            for (int off = 1; off <= 8; off <<= 1)
                sm += __shfl_xor(sm, off, 64);
            const float a = e / sm;
            alf[tid] = a;
            out[(size_t)ROUTED_SIZE + bt * NBLK + tid] = a;   // alpha_bth
        }
        BAR();

        // ---- routed partial over this thread's 4 planes -> LDS combine ----
        {
            const float a0 = alf[4 * g], a1 = alf[4 * g + 1];
            const float a2 = alf[4 * g + 2], a3 = alf[4 * g + 3];
            rp[g][c] = a0 * v[j][0] + a1 * v[j][1] + a2 * v[j][2] + a3 * v[j][3];
        }
        BAR();
        if (g == 0) {
            const v4f r = (rp[0][c] + rp[1][c]) + (rp[2][c] + rp[3][c]);
            __builtin_nontemporal_store(r, (v4f*)(out + bt * H + h0));
        }
        if (j + 1 < TCOLS) BAR();   // guard pv/rp/scores/alf reuse by next col
    }
}

extern "C" void kernel_launch(void* const* d_in, const int* in_sizes, int n_in,
                              void* d_out, int out_size, void* d_ws, size_t ws_size,
                              hipStream_t stream) {
    const float* values       = (const float*)d_in[0];
    const float* w_query      = (const float*)d_in[1];
    const float* key_pos_bias = (const float*)d_in[2];
    const int*   position     = (const int*)d_in[3];
    float*       out          = (float*)d_out;
    float*       qb           = (float*)d_ws;   // 16 floats of scratch

    hipLaunchKernelGGL(qb_kernel, dim3(1), dim3(1024), 0, stream,
                       w_query, key_pos_bias, position, qb);
    hipLaunchKernelGGL(block_attn_res_kernel, dim3(BT / TCOLS), dim3(1024), 0, stream,
                       values, w_query, position, qb, out);
}